// Round 2
// baseline (140408.557 us; speedup 1.0000x reference)
//
#include <hip/hip_runtime.h>
#include <cstdint>
#include <cstddef>

#define L_SEQ 4096
#define HDIM  1024
#define G3    3072          // 3*HDIM
#define NWG   128           // workgroups per direction (scan)
#define SCAN_THREADS 256

// ---------------------------------------------------------------------------
// GEMM: GI[s][r] = sum_k X[s][k] * W[r][k] + b[r]   (both operands k-major)
// 128x128 tile, BK=16, 256 threads, 8x8 micro-tile per thread.
// ---------------------------------------------------------------------------
#define BM 128
#define BN 128
#define BK 16
#define LPAD 4

__global__ __launch_bounds__(256) void gi_gemm(
    const float* __restrict__ X,
    const float* __restrict__ Wf, const float* __restrict__ bf,
    const float* __restrict__ Wr, const float* __restrict__ br,
    float* __restrict__ GIf, float* __restrict__ GIr)
{
    const int dir = blockIdx.z;
    const float* W  = dir ? Wr : Wf;
    const float* bi = dir ? br : bf;
    float* GI = dir ? GIr : GIf;

    __shared__ float As[BK][BM + LPAD];
    __shared__ float Bs[BK][BN + LPAD];

    const int t  = threadIdx.x;
    const int s0 = blockIdx.x * BM;
    const int r0 = blockIdx.y * BN;

    const int tr = t >> 4;          // 0..15
    const int tc = t & 15;          // 0..15

    float acc[8][8];
#pragma unroll
    for (int i = 0; i < 8; ++i)
#pragma unroll
        for (int j = 0; j < 8; ++j) acc[i][j] = 0.f;

    const int lrow = t >> 2;        // 0..63
    const int lcol = (t & 3) * 4;   // 0,4,8,12

    for (int k0 = 0; k0 < HDIM; k0 += BK) {
#pragma unroll
        for (int p = 0; p < 2; ++p) {
            const int row = lrow + 64 * p;
            float4 av = *reinterpret_cast<const float4*>(&X[(size_t)(s0 + row) * HDIM + k0 + lcol]);
            float4 bv = *reinterpret_cast<const float4*>(&W[(size_t)(r0 + row) * HDIM + k0 + lcol]);
            As[lcol + 0][row] = av.x; As[lcol + 1][row] = av.y;
            As[lcol + 2][row] = av.z; As[lcol + 3][row] = av.w;
            Bs[lcol + 0][row] = bv.x; Bs[lcol + 1][row] = bv.y;
            Bs[lcol + 2][row] = bv.z; Bs[lcol + 3][row] = bv.w;
        }
        __syncthreads();
#pragma unroll
        for (int kk = 0; kk < BK; ++kk) {
            float4 a0 = *reinterpret_cast<const float4*>(&As[kk][8 * tr]);
            float4 a1 = *reinterpret_cast<const float4*>(&As[kk][8 * tr + 4]);
            float4 b0 = *reinterpret_cast<const float4*>(&Bs[kk][8 * tc]);
            float4 b1 = *reinterpret_cast<const float4*>(&Bs[kk][8 * tc + 4]);
            float a[8] = {a0.x, a0.y, a0.z, a0.w, a1.x, a1.y, a1.z, a1.w};
            float b[8] = {b0.x, b0.y, b0.z, b0.w, b1.x, b1.y, b1.z, b1.w};
#pragma unroll
            for (int i = 0; i < 8; ++i)
#pragma unroll
                for (int j = 0; j < 8; ++j)
                    acc[i][j] = fmaf(a[i], b[j], acc[i][j]);
        }
        __syncthreads();
    }

#pragma unroll
    for (int i = 0; i < 8; ++i) {
        const int row = s0 + 8 * tr + i;
#pragma unroll
        for (int j = 0; j < 8; ++j) acc[i][j] += bi[r0 + 8 * tc + j];
        float4* dst = reinterpret_cast<float4*>(&GI[(size_t)row * G3 + r0 + 8 * tc]);
        dst[0] = make_float4(acc[i][0], acc[i][1], acc[i][2], acc[i][3]);
        dst[1] = make_float4(acc[i][4], acc[i][5], acc[i][6], acc[i][7]);
    }
}

// ---------------------------------------------------------------------------
// Persistent bidirectional GRU scan.
// 256 WGs: 0..127 forward, 128..255 reverse. Each WG owns 8 rows of h.
// Whh rows for those 8 h elements (3 gates) live in REGISTERS (96/thread).
// Flag barrier: flg[wid] = steps completed; consumers poll + acquire fence.
// h double-buffered in global ws. bufs/flags zeroed by memset before launch.
// GI is register-double-buffered: loads for step s+1 issue AFTER the acquire
// fence of step s (so the fence's vmcnt(0) never serializes them) and are
// consumed in step s+1.
// ---------------------------------------------------------------------------
__global__ __launch_bounds__(SCAN_THREADS, 1) void gru_scan(
    const float* __restrict__ WhhF, const float* __restrict__ WhhR,
    const float* __restrict__ bhhF, const float* __restrict__ bhhR,
    const float* __restrict__ GIf,  const float* __restrict__ GIr,
    float* __restrict__ out, float* __restrict__ hbuf, int* __restrict__ flags)
{
    const int wg  = blockIdx.x;
    const int dir = wg >> 7;            // 0 fwd, 1 rev
    const int wid = wg & (NWG - 1);
    const float* Whh = dir ? WhhR : WhhF;
    const float* bhh = dir ? bhhR : bhhF;
    const float* GI  = dir ? GIr  : GIf;
    float* hb = hbuf + dir * (2 * HDIM);
    int*   flg = flags + dir * 256;

    const int t     = threadIdx.x;
    const int r_idx = t >> 5;           // 0..7
    const int kp    = t & 31;           // 0..31
    const int j     = wid * 8 + r_idx;  // global h index this group serves

    // weights -> registers (one-time). Row j (gate r), j+H (z), j+2H (n)
    float wr[32], wz[32], wn[32];
    {
        const float* pr = Whh + (size_t)j * HDIM + kp;
        const float* pz = pr + (size_t)HDIM * HDIM;
        const float* pn = pz + (size_t)HDIM * HDIM;
#pragma unroll
        for (int i = 0; i < 32; ++i) {
            wr[i] = pr[32 * i];
            wz[i] = pz[32 * i];
            wn[i] = pn[32 * i];
        }
    }
    const float b_r = bhh[j];
    const float b_z = bhh[HDIM + j];
    const float b_n = bhh[2 * HDIM + j];

    __shared__ float h_lds[HDIM];

    // preload GI for step 0
    float gr = 0.f, gz = 0.f, gn = 0.f;
    if (kp == 0) {
        const float* g = GI + (size_t)(dir ? (L_SEQ - 1) : 0) * G3 + j;
        gr = g[0];
        gz = g[HDIM];
        gn = g[2 * HDIM];
    }

    for (int s = 0; s < L_SEQ; ++s) {
        const int srow = dir ? (L_SEQ - 1 - s) : s;

        // wait until every WG of this direction finished step s-1
        if (s > 0 && t < NWG) {
            while (__hip_atomic_load(&flg[t], __ATOMIC_RELAXED, __HIP_MEMORY_SCOPE_AGENT) < s) {
            }
        }
        __syncthreads();
        __threadfence();   // acquire: invalidate stale cached copies of h

        // stage h (4KB) into LDS
        const float4 hv = reinterpret_cast<const float4*>(hb + (size_t)(s & 1) * HDIM)[t];
        reinterpret_cast<float4*>(h_lds)[t] = hv;

        // prefetch GI for step s+1 (register double-buffer) — overlaps with
        // h staging + dot product; consumed next iteration
        float gnr = 0.f, gnz = 0.f, gnn = 0.f;
        if (s + 1 < L_SEQ && kp == 0) {
            const int nrow = dir ? (L_SEQ - 2 - s) : (s + 1);
            const float* g = GI + (size_t)nrow * G3 + j;
            gnr = g[0];
            gnz = g[HDIM];
            gnn = g[2 * HDIM];
        }
        __syncthreads();

        // partial dot products: k = kp + 32*i  (conflict-free LDS pattern)
        float ar = 0.f, az = 0.f, an = 0.f;
#pragma unroll
        for (int i = 0; i < 32; ++i) {
            const float h = h_lds[kp + 32 * i];
            ar = fmaf(wr[i], h, ar);
            az = fmaf(wz[i], h, az);
            an = fmaf(wn[i], h, an);
        }
        // reduce across the 32 k-lanes
#pragma unroll
        for (int off = 16; off > 0; off >>= 1) {
            ar += __shfl_down(ar, off, 32);
            az += __shfl_down(az, off, 32);
            an += __shfl_down(an, off, 32);
        }

        float hn = 0.f;
        if (kp == 0) {
            const float hold = h_lds[j];
            const float rr = 1.f / (1.f + __expf(-(gr + ar + b_r)));
            const float zz = 1.f / (1.f + __expf(-(gz + az + b_z)));
            const float xx = gn + rr * (an + b_n);
            // overflow-safe fast tanh
            const float e  = __expf(-2.f * fabsf(xx));
            float th = (1.f - e) / (1.f + e);
            th = copysignf(th, xx);
            hn = (1.f - zz) * th + zz * hold;
            hb[(size_t)((s + 1) & 1) * HDIM + j] = hn;
        }

        __threadfence();   // release: make h stores visible at agent scope
        __syncthreads();
        if (t == 0)
            __hip_atomic_store(&flg[wid], s + 1, __ATOMIC_RELAXED, __HIP_MEMORY_SCOPE_AGENT);

        // out stores AFTER the flag publish — nobody consumes them, keep the
        // release fence from waiting on these HBM store acks
        if (kp == 0) {
            out[(size_t)srow * (2 * HDIM) + dir * HDIM + j] = hn;
            if (s == L_SEQ - 1) {
                out[(size_t)L_SEQ * 2 * HDIM + dir * HDIM + j] = hn;             // hidden
                out[(size_t)L_SEQ * 2 * HDIM + 2 * HDIM + dir * HDIM + j] = hn;  // projected
            }
        }

        gr = gnr; gz = gnz; gn = gnn;
    }
}

// ---------------------------------------------------------------------------
extern "C" void kernel_launch(void* const* d_in, const int* in_sizes, int n_in,
                              void* d_out, int out_size, void* d_ws, size_t ws_size,
                              hipStream_t stream)
{
    (void)in_sizes; (void)n_in; (void)out_size; (void)ws_size;

    const float* x    = (const float*)d_in[0];
    const float* fWih = (const float*)d_in[1];
    const float* fWhh = (const float*)d_in[2];
    const float* fbih = (const float*)d_in[3];
    const float* fbhh = (const float*)d_in[4];
    const float* rWih = (const float*)d_in[5];
    const float* rWhh = (const float*)d_in[6];
    const float* rbih = (const float*)d_in[7];
    const float* rbhh = (const float*)d_in[8];
    float* out = (float*)d_out;

    float* ws    = (float*)d_ws;
    int*   flags = (int*)ws;                       // ints [0,1024) (zeroed)
    float* hbuf  = ws + 1024;                      // floats [1024,5120)
    float* GIf   = ws + 8192;                      // L*3072 floats
    float* GIr   = GIf + (size_t)L_SEQ * G3;       // L*3072 floats

    // flags + h double-buffers must be zero (ws is poisoned 0xAA each launch)
    hipMemsetAsync(d_ws, 0, 8192 * sizeof(float), stream);

    dim3 gg(L_SEQ / BM, G3 / BN, 2);
    gi_gemm<<<gg, 256, 0, stream>>>(x, fWih, fbih, rWih, rbih, GIf, GIr);

    const float* a0 = fWhh; const float* a1 = rWhh;
    const float* a2 = fbhh; const float* a3 = rbhh;
    const float* a4 = GIf;  const float* a5 = GIr;
    float* a6 = out; float* a7 = hbuf; int* a8 = flags;
    void* args[] = {(void*)&a0, (void*)&a1, (void*)&a2, (void*)&a3,
                    (void*)&a4, (void*)&a5, (void*)&a6, (void*)&a7, (void*)&a8};

    hipError_t err = hipLaunchCooperativeKernel((const void*)gru_scan,
                                                dim3(2 * NWG), dim3(SCAN_THREADS),
                                                args, 0, stream);
    if (err != hipSuccess) {
        // fall back to a regular launch (256 WGs on 256 CUs co-reside)
        gru_scan<<<dim3(2 * NWG), dim3(SCAN_THREADS), 0, stream>>>(
            fWhh, rWhh, fbhh, rbhh, GIf, GIr, out, hbuf, flags);
    }
}

// Round 4
// 9589.953 us; speedup vs baseline: 14.6412x; 14.6412x over previous
//
#include <hip/hip_runtime.h>
#include <cstdint>
#include <cstddef>

#define L_SEQ 4096
#define HDIM  1024
#define G3    3072          // 3*HDIM
#define NWG   128           // workgroups per direction (scan)
#define SCAN_THREADS 256

// ---------------------------------------------------------------------------
// GEMM: GI[s][r] = sum_k X[s][k] * W[r][k] + b[r]   (both operands k-major)
// 128x128 tile, BK=16, 256 threads, 8x8 micro-tile per thread.
// ---------------------------------------------------------------------------
#define BM 128
#define BN 128
#define BK 16
#define LPAD 4

__global__ __launch_bounds__(256) void gi_gemm(
    const float* __restrict__ X,
    const float* __restrict__ Wf, const float* __restrict__ bf,
    const float* __restrict__ Wr, const float* __restrict__ br,
    float* __restrict__ GIf, float* __restrict__ GIr)
{
    const int dir = blockIdx.z;
    const float* W  = dir ? Wr : Wf;
    const float* bi = dir ? br : bf;
    float* GI = dir ? GIr : GIf;

    __shared__ float As[BK][BM + LPAD];
    __shared__ float Bs[BK][BN + LPAD];

    const int t  = threadIdx.x;
    const int s0 = blockIdx.x * BM;
    const int r0 = blockIdx.y * BN;

    const int tr = t >> 4;          // 0..15
    const int tc = t & 15;          // 0..15

    float acc[8][8];
#pragma unroll
    for (int i = 0; i < 8; ++i)
#pragma unroll
        for (int j = 0; j < 8; ++j) acc[i][j] = 0.f;

    const int lrow = t >> 2;        // 0..63
    const int lcol = (t & 3) * 4;   // 0,4,8,12

    for (int k0 = 0; k0 < HDIM; k0 += BK) {
#pragma unroll
        for (int p = 0; p < 2; ++p) {
            const int row = lrow + 64 * p;
            float4 av = *reinterpret_cast<const float4*>(&X[(size_t)(s0 + row) * HDIM + k0 + lcol]);
            float4 bv = *reinterpret_cast<const float4*>(&W[(size_t)(r0 + row) * HDIM + k0 + lcol]);
            As[lcol + 0][row] = av.x; As[lcol + 1][row] = av.y;
            As[lcol + 2][row] = av.z; As[lcol + 3][row] = av.w;
            Bs[lcol + 0][row] = bv.x; Bs[lcol + 1][row] = bv.y;
            Bs[lcol + 2][row] = bv.z; Bs[lcol + 3][row] = bv.w;
        }
        __syncthreads();
#pragma unroll
        for (int kk = 0; kk < BK; ++kk) {
            float4 a0 = *reinterpret_cast<const float4*>(&As[kk][8 * tr]);
            float4 a1 = *reinterpret_cast<const float4*>(&As[kk][8 * tr + 4]);
            float4 b0 = *reinterpret_cast<const float4*>(&Bs[kk][8 * tc]);
            float4 b1 = *reinterpret_cast<const float4*>(&Bs[kk][8 * tc + 4]);
            float a[8] = {a0.x, a0.y, a0.z, a0.w, a1.x, a1.y, a1.z, a1.w};
            float b[8] = {b0.x, b0.y, b0.z, b0.w, b1.x, b1.y, b1.z, b1.w};
#pragma unroll
            for (int i = 0; i < 8; ++i)
#pragma unroll
                for (int j = 0; j < 8; ++j)
                    acc[i][j] = fmaf(a[i], b[j], acc[i][j]);
        }
        __syncthreads();
    }

#pragma unroll
    for (int i = 0; i < 8; ++i) {
        const int row = s0 + 8 * tr + i;
#pragma unroll
        for (int j = 0; j < 8; ++j) acc[i][j] += bi[r0 + 8 * tc + j];
        float4* dst = reinterpret_cast<float4*>(&GI[(size_t)row * G3 + r0 + 8 * tc]);
        dst[0] = make_float4(acc[i][0], acc[i][1], acc[i][2], acc[i][3]);
        dst[1] = make_float4(acc[i][4], acc[i][5], acc[i][6], acc[i][7]);
    }
}

// ---------------------------------------------------------------------------
// Persistent bidirectional GRU scan — LOCK-FREE TAGGED PACKETS, NO FENCES.
//
// Each h element is published as an 8-byte packet (tag:u32 << 32 | f32 bits)
// via relaxed agent-scope atomics (coherent at the LLC, no L2 writeback/
// invalidate storms — round 2's __threadfence pair cost 33 us/step).
// Packet atomicity fuses data+flag: if a consumer sees tag==s, the value in
// the same packet IS h_s[j]. No ordering primitives in the loop at all.
//
// Packet overwrite safety (slot j, parity p, tag s-1 -> s+1): the writer
// finished step s's poll+barrier, so it observed tag-s packets from ALL WGs;
// a WG publishes tag s only after its step-(s-1) mid-step __syncthreads,
// which follows every one of its threads reading the tag-(s-1) packets.
//
// h_lds race fix (vs round-2 design): h_lds is DOUBLE-BUFFERED by parity.
// A thread may only reach staging of parity p at step s+2 after passing step
// s+1's __syncthreads, which by program order guarantees the whole WG
// finished step s's dot-product reads of parity p. One barrier per step.
//
// Whh rows live in REGISTERS (96 floats/thread), pinned by an asm barrier so
// the compiler cannot sink the loads back into the loop (round-2 VGPR=72 bug).
// ---------------------------------------------------------------------------
__global__ __launch_bounds__(SCAN_THREADS, 1) void gru_scan(
    const float* __restrict__ WhhF, const float* __restrict__ WhhR,
    const float* __restrict__ bhhF, const float* __restrict__ bhhR,
    const float* __restrict__ GIf,  const float* __restrict__ GIr,
    float* __restrict__ out,
    unsigned long long* __restrict__ pkF, unsigned long long* __restrict__ pkR)
{
    const int wg  = blockIdx.x;
    const int dir = wg >> 7;            // 0 fwd, 1 rev
    const int wid = wg & (NWG - 1);
    const float* Whh = dir ? WhhR : WhhF;
    const float* bhh = dir ? bhhR : bhhF;
    const float* GI  = dir ? GIr  : GIf;
    unsigned long long* pk = dir ? pkR : pkF;

    const int t     = threadIdx.x;
    const int r_idx = t >> 5;           // 0..7
    const int kp    = t & 31;           // 0..31
    const int j     = wid * 8 + r_idx;  // global h index this group serves

    // weights -> registers (one-time). Row j (gate r), j+H (z), j+2H (n)
    float wr[32], wz[32], wn[32];
    {
        const float* pr = Whh + (size_t)j * HDIM + kp;
        const float* pz = pr + (size_t)HDIM * HDIM;
        const float* pn = pz + (size_t)HDIM * HDIM;
#pragma unroll
        for (int i = 0; i < 32; ++i) {
            wr[i] = pr[32 * i];
            wz[i] = pz[32 * i];
            wn[i] = pn[32 * i];
        }
    }
    // pin in VGPRs: the asm may "modify" the values, so the compiler cannot
    // rematerialize the global loads inside the step loop.
#pragma unroll
    for (int i = 0; i < 32; ++i) {
        asm volatile("" : "+v"(wr[i]), "+v"(wz[i]), "+v"(wn[i]));
    }
    const float b_r = bhh[j];
    const float b_z = bhh[HDIM + j];
    const float b_n = bhh[2 * HDIM + j];

    __shared__ float h_lds[2][HDIM];    // double-buffered by step parity

    // preload GI for step 0
    float gr = 0.f, gz = 0.f, gn = 0.f;
    if (kp == 0) {
        const float* g = GI + (size_t)(dir ? (L_SEQ - 1) : 0) * G3 + j;
        gr = g[0];
        gz = g[HDIM];
        gn = g[2 * HDIM];
    }

    for (int s = 0; s < L_SEQ; ++s) {
        const int srow = dir ? (L_SEQ - 1 - s) : s;
        const int par  = s & 1;

        // ---- poll the 4 packets this thread stages (tag must equal s) ----
        const unsigned long long* src = pk + (size_t)par * HDIM + 4 * t;
        const unsigned want = (unsigned)s;
        unsigned long long p0, p1, p2, p3;
        for (;;) {
            p0 = __hip_atomic_load(src + 0, __ATOMIC_RELAXED, __HIP_MEMORY_SCOPE_AGENT);
            p1 = __hip_atomic_load(src + 1, __ATOMIC_RELAXED, __HIP_MEMORY_SCOPE_AGENT);
            p2 = __hip_atomic_load(src + 2, __ATOMIC_RELAXED, __HIP_MEMORY_SCOPE_AGENT);
            p3 = __hip_atomic_load(src + 3, __ATOMIC_RELAXED, __HIP_MEMORY_SCOPE_AGENT);
            if ((unsigned)(p0 >> 32) == want && (unsigned)(p1 >> 32) == want &&
                (unsigned)(p2 >> 32) == want && (unsigned)(p3 >> 32) == want)
                break;
        }
        reinterpret_cast<float4*>(h_lds[par])[t] =
            make_float4(__uint_as_float((unsigned)p0), __uint_as_float((unsigned)p1),
                        __uint_as_float((unsigned)p2), __uint_as_float((unsigned)p3));

        // prefetch GI for step s+1 (register double-buffer) — overlaps dot
        float gnr = 0.f, gnz = 0.f, gnn = 0.f;
        if (s + 1 < L_SEQ && kp == 0) {
            const int nrow = dir ? (L_SEQ - 2 - s) : (s + 1);
            const float* g = GI + (size_t)nrow * G3 + j;
            gnr = g[0];
            gnz = g[HDIM];
            gnn = g[2 * HDIM];
        }
        __syncthreads();

        // partial dot products: k = kp + 32*i (same-address broadcast in LDS)
        float ar = 0.f, az = 0.f, an = 0.f;
#pragma unroll
        for (int i = 0; i < 32; ++i) {
            const float h = h_lds[par][kp + 32 * i];
            ar = fmaf(wr[i], h, ar);
            az = fmaf(wz[i], h, az);
            an = fmaf(wn[i], h, an);
        }
        // reduce across the 32 k-lanes
#pragma unroll
        for (int off = 16; off > 0; off >>= 1) {
            ar += __shfl_down(ar, off, 32);
            az += __shfl_down(az, off, 32);
            an += __shfl_down(an, off, 32);
        }

        if (kp == 0) {
            const float hold = h_lds[par][j];
            const float rr = 1.f / (1.f + __expf(-(gr + ar + b_r)));
            const float zz = 1.f / (1.f + __expf(-(gz + az + b_z)));
            const float xx = gn + rr * (an + b_n);
            const float e  = __expf(-2.f * fabsf(xx));   // overflow-safe tanh
            float th = (1.f - e) / (1.f + e);
            th = copysignf(th, xx);
            const float hn = (1.f - zz) * th + zz * hold;

            // publish FIRST (critical path), then ordinary out stores
            const unsigned long long pkt =
                ((unsigned long long)(unsigned)(s + 1) << 32) | __float_as_uint(hn);
            __hip_atomic_store(pk + (size_t)((s + 1) & 1) * HDIM + j, pkt,
                               __ATOMIC_RELAXED, __HIP_MEMORY_SCOPE_AGENT);

            out[(size_t)srow * (2 * HDIM) + dir * HDIM + j] = hn;
            if (s == L_SEQ - 1) {
                out[(size_t)L_SEQ * 2 * HDIM + dir * HDIM + j] = hn;             // hidden
                out[(size_t)L_SEQ * 2 * HDIM + 2 * HDIM + dir * HDIM + j] = hn;  // projected
            }
        }

        gr = gnr; gz = gnz; gn = gnn;
    }
}

// ---------------------------------------------------------------------------
extern "C" void kernel_launch(void* const* d_in, const int* in_sizes, int n_in,
                              void* d_out, int out_size, void* d_ws, size_t ws_size,
                              hipStream_t stream)
{
    (void)in_sizes; (void)n_in; (void)out_size; (void)ws_size;

    const float* x    = (const float*)d_in[0];
    const float* fWih = (const float*)d_in[1];
    const float* fWhh = (const float*)d_in[2];
    const float* fbih = (const float*)d_in[3];
    const float* fbhh = (const float*)d_in[4];
    const float* rWih = (const float*)d_in[5];
    const float* rWhh = (const float*)d_in[6];
    const float* rbih = (const float*)d_in[7];
    const float* rbhh = (const float*)d_in[8];
    float* out = (float*)d_out;

    // ws layout (bytes):
    //   [0, 16384)      pkF : 2 parities x 1024 x u64
    //   [16384, 32768)  pkR
    //   [32768, ...)    GIf (L*3072 f32), then GIr
    unsigned long long* pkF = (unsigned long long*)d_ws;
    unsigned long long* pkR = pkF + 2 * HDIM;
    float* GIf = (float*)((char*)d_ws + 32768);
    float* GIr = GIf + (size_t)L_SEQ * G3;

    // packets must start as tag=0 value=0.0f (= h_0); ws is poisoned 0xAA
    hipMemsetAsync(d_ws, 0, 32768, stream);

    dim3 gg(L_SEQ / BM, G3 / BN, 2);
    gi_gemm<<<gg, 256, 0, stream>>>(x, fWih, fbih, rWih, rbih, GIf, GIr);

    const float* a0 = fWhh; const float* a1 = rWhh;
    const float* a2 = fbhh; const float* a3 = rbhh;
    const float* a4 = GIf;  const float* a5 = GIr;
    float* a6 = out;
    unsigned long long* a7 = pkF; unsigned long long* a8 = pkR;
    void* args[] = {(void*)&a0, (void*)&a1, (void*)&a2, (void*)&a3,
                    (void*)&a4, (void*)&a5, (void*)&a6, (void*)&a7, (void*)&a8};

    hipError_t err = hipLaunchCooperativeKernel((const void*)gru_scan,
                                                dim3(2 * NWG), dim3(SCAN_THREADS),
                                                args, 0, stream);
    if (err != hipSuccess) {
        // fall back to a regular launch (256 WGs on 256 CUs co-reside)
        gru_scan<<<dim3(2 * NWG), dim3(SCAN_THREADS), 0, stream>>>(
            fWhh, rWhh, fbhh, rbhh, GIf, GIr, out, pkF, pkR);
    }
}